// Round 1
// baseline (370.123 us; speedup 1.0000x reference)
//
#include <hip/hip_runtime.h>

#define NPTS   16384
#define NDIM   64
#define NBATCH 8
#define TB     1024
#define VPT    16      // NPTS / TB
#define NB     8192    // histogram bins
#define BPT    8       // NB / TB
#define EPSF   0.1f
#define MINS   5
#define NCMAX  512
#define BIGI   0x3fffffff

// ---------------- transpose (B,N,D) -> (B,D,N) ----------------
__global__ void ktrans(const float* __restrict__ f, float* __restrict__ xt) {
  __shared__ float tile[64][65];
  int blk = blockIdx.x;
  int b   = blk >> 8;                 // 256 n-tiles per batch
  int n0  = (blk & 255) << 6;
  for (int i = threadIdx.x; i < 64 * 64; i += 256) {
    int n = i >> 6, d = i & 63;
    tile[n][d] = f[((size_t)b * NPTS + n0 + n) * NDIM + d];
  }
  __syncthreads();
  for (int i = threadIdx.x; i < 64 * 64; i += 256) {
    int d = i >> 6, n = i & 63;
    xt[((size_t)b * NDIM + d) * NPTS + n0 + n] = tile[n][d];
  }
}

// ---------------- helpers ----------------
__device__ __forceinline__ int binof(float x, float mn, float inv) {
  float fb = (x - mn) * inv;
  int b = (int)fb;
  if (fb < 0.f) b = 0;
  if (b > NB - 1) b = NB - 1;
  return b;
}

__device__ __forceinline__ int cnt_le(float v, float mn, float inv,
                                      const unsigned int* offs, const float* xs) {
  float fb = (v - mn) * inv;
  int b = (int)fb;
  if (fb < 0.f) b = 0;
  if (b > NB - 1) b = NB - 1;
  int s0 = b ? (int)offs[b - 1] : 0;
  int e0 = (int)offs[b];
  int c = s0;
  for (int i = s0; i < e0; ++i) c += (xs[i] <= v) ? 1 : 0;
  return c;
}

__device__ __forceinline__ int cnt_lt(float v, float mn, float inv,
                                      const unsigned int* offs, const float* xs) {
  float fb = (v - mn) * inv;
  int b = (int)fb;
  if (fb < 0.f) b = 0;
  if (b > NB - 1) b = NB - 1;
  int s0 = b ? (int)offs[b - 1] : 0;
  int e0 = (int)offs[b];
  int c = s0;
  for (int i = s0; i < e0; ++i) c += (xs[i] < v) ? 1 : 0;
  return c;
}

// forward-scan monoid: (has core, first core val, last core val, last core idx,
//                       #internal cluster starts among non-first cores)
struct FS { int h; float f; float l; int li; int c; };
__device__ __forceinline__ FS fsid() { FS r; r.h = 0; r.f = 0.f; r.l = 0.f; r.li = -1; r.c = 0; return r; }
__device__ __forceinline__ FS fscomb(FS a, FS b) {
  FS r;
  r.h  = a.h | b.h;
  r.f  = a.h ? a.f : b.f;
  r.l  = b.h ? b.l : a.l;
  r.li = b.h ? b.li : a.li;
  int gap = (a.h && b.h && ((b.f - a.l) > EPSF)) ? 1 : 0;
  r.c  = a.c + b.c + gap;
  return r;
}

// ---------------- per-(b,d) exact 1-D DBSCAN ----------------
__global__ void __launch_bounds__(TB) kdbscan(const float* __restrict__ xt,
                                              short* __restrict__ labels,
                                              int* __restrict__ nclg) {
  const int tid  = threadIdx.x;
  const int lane = tid & 63;
  const int wid  = tid >> 6;
  const int bd   = blockIdx.x;
  const float* __restrict__ x = xt + (size_t)bd * NPTS;

  __shared__ float xs[NPTS];            // 64 KB : sorted values
  __shared__ unsigned int hist[NB];     // 32 KB : histogram, later aliased as lab[]
  __shared__ unsigned int offs[NB];     // 32 KB : bin ends after scatter
  __shared__ float wmn[16], wmx[16];
  __shared__ unsigned int wsum[16];
  __shared__ int   sh[16];  __shared__ float sf[16], sl[16];
  __shared__ int   sli[16]; __shared__ int   sc[16];
  __shared__ int   wrr[16];
  short* lab = (short*)hist;            // labels per sorted position (alias of hist)

  // ---- 1. min / max ----
  float mn = INFINITY, mx = -INFINITY;
  for (int s = 0; s < VPT; ++s) {
    float v = x[tid + s * TB];
    mn = fminf(mn, v); mx = fmaxf(mx, v);
  }
  for (int d = 1; d < 64; d <<= 1) {
    mn = fminf(mn, __shfl_xor(mn, d));
    mx = fmaxf(mx, __shfl_xor(mx, d));
  }
  if (lane == 0) { wmn[wid] = mn; wmx[wid] = mx; }
  __syncthreads();
  mn = wmn[0]; mx = wmx[0];
  for (int w = 1; w < 16; ++w) { mn = fminf(mn, wmn[w]); mx = fmaxf(mx, wmx[w]); }
  float range = mx - mn;
  float inv = (range > 0.f) ? ((float)NB / range) : 0.f;

  // ---- 2. histogram ----
  for (int i = tid; i < NB; i += TB) hist[i] = 0u;
  __syncthreads();
  for (int s = 0; s < VPT; ++s) {
    float v = x[tid + s * TB];
    atomicAdd(&hist[binof(v, mn, inv)], 1u);
  }
  __syncthreads();

  // ---- 3. exclusive prefix sum -> offs ----
  unsigned int loc[BPT];
  unsigned int run = 0;
  const int bbase = tid * BPT;
  for (int j = 0; j < BPT; ++j) { loc[j] = run; run += hist[bbase + j]; }
  unsigned int incl = run;
  for (int d = 1; d < 64; d <<= 1) {
    unsigned int u = __shfl_up(incl, d);
    if (lane >= d) incl += u;
  }
  unsigned int exc = __shfl_up(incl, 1);
  if (lane == 0) exc = 0u;
  if (lane == 63) wsum[wid] = incl;
  __syncthreads();
  unsigned int wb = 0;
  for (int w = 0; w < wid; ++w) wb += wsum[w];
  unsigned int tb0 = wb + exc;
  for (int j = 0; j < BPT; ++j) offs[bbase + j] = tb0 + loc[j];
  __syncthreads();

  // ---- 4. scatter into bins ----
  for (int s = 0; s < VPT; ++s) {
    float v = x[tid + s * TB];
    unsigned int p = atomicAdd(&offs[binof(v, mn, inv)], 1u);
    xs[p] = v;
  }
  __syncthreads();   // offs[b] now = end of bin b

  // ---- 5. insertion sort inside each bin ----
  for (int j = 0; j < BPT; ++j) {
    int b = bbase + j;
    int s0 = b ? (int)offs[b - 1] : 0;
    int e0 = (int)offs[b];
    for (int i = s0 + 1; i < e0; ++i) {
      float key = xs[i];
      int k = i - 1;
      while (k >= s0 && xs[k] > key) { xs[k + 1] = xs[k]; --k; }
      xs[k + 1] = key;
    }
  }
  __syncthreads();   // xs fully sorted ascending

  // ---- 6. core flags (exact range counts, bin-accelerated) ----
  const int p0 = tid * VPT;
  unsigned int coremask = 0u;
  for (int s = 0; s < VPT; ++s) {
    float xi = xs[p0 + s];
    int hi = cnt_le(xi + EPSF, mn, inv, offs, xs);
    int lo = cnt_lt(xi - EPSF, mn, inv, offs, xs);
    if (hi - lo >= MINS) coremask |= (1u << s);
  }

  // ---- 7. forward scan: prev core val/idx + cluster-start count ----
  FS ch = fsid();
  for (int s = 0; s < VPT; ++s) {
    if ((coremask >> s) & 1u) {
      float xv = xs[p0 + s];
      if (!ch.h) { ch.h = 1; ch.f = xv; }
      else if ((xv - ch.l) > EPSF) ++ch.c;
      ch.l = xv; ch.li = p0 + s;
    }
  }
  FS cur = ch;
  for (int d = 1; d < 64; d <<= 1) {
    FS u;
    u.h  = __shfl_up(cur.h, d);
    u.f  = __shfl_up(cur.f, d);
    u.l  = __shfl_up(cur.l, d);
    u.li = __shfl_up(cur.li, d);
    u.c  = __shfl_up(cur.c, d);
    FS cmb = fscomb(u, cur);
    if (lane >= d) cur = cmb;
  }
  FS exs;
  exs.h  = __shfl_up(cur.h, 1);
  exs.f  = __shfl_up(cur.f, 1);
  exs.l  = __shfl_up(cur.l, 1);
  exs.li = __shfl_up(cur.li, 1);
  exs.c  = __shfl_up(cur.c, 1);
  if (lane == 0) exs = fsid();
  if (lane == 63) { sh[wid] = cur.h; sf[wid] = cur.f; sl[wid] = cur.l; sli[wid] = cur.li; sc[wid] = cur.c; }
  __syncthreads();
  FS pre = fsid();
  for (int w = 0; w < wid; ++w) {
    FS t; t.h = sh[w]; t.f = sf[w]; t.l = sl[w]; t.li = sli[w]; t.c = sc[w];
    pre = fscomb(pre, t);
  }
  FS sp = fscomb(pre, exs);

  float P  = sp.h ? sp.l  : -INFINITY;
  int   Pi = sp.h ? sp.li : -1;
  int starts = sp.h ? (sp.c + 1) : 0;
  int li[VPT];
  #pragma unroll
  for (int s = 0; s < VPT; ++s) {
    int i = p0 + s;
    if ((coremask >> s) & 1u) {
      float xv = xs[i];
      if ((xv - P) > EPSF) ++starts;
      P = xv; Pi = i;
      lab[i] = (short)(starts - 1);   // core label = cid
    }
    li[s] = Pi;
  }
  if (tid == TB - 1) nclg[bd] = starts;
  __syncthreads();

  // ---- 8. backward scan (first core idx >= i) + border labels ----
  int fidx = BIGI;
  for (int s = VPT - 1; s >= 0; --s)
    if ((coremask >> s) & 1u) fidx = p0 + s;
  int rin = fidx;
  for (int d = 1; d < 64; d <<= 1) {
    int u = __shfl_down(rin, d);
    if (lane < 64 - d) rin = min(rin, u);
  }
  int rex = __shfl_down(rin, 1);
  if (lane == 63) rex = BIGI;
  if (lane == 0) wrr[wid] = rin;
  __syncthreads();
  int R = rex;
  for (int w = wid + 1; w < 16; ++w) R = min(R, wrr[w]);
  #pragma unroll
  for (int s = VPT - 1; s >= 0; --s) {
    int i = p0 + s;
    if ((coremask >> s) & 1u) {
      R = i;
    } else {
      int l_ = li[s];
      float xi = xs[i];
      float dl = (l_ >= 0)  ? (xi - xs[l_]) : INFINITY;
      float dr = (R < NPTS) ? (xs[R] - xi)  : INFINITY;
      short lb = -1;
      if (fminf(dl, dr) <= EPSF)
        lb = (dl <= dr) ? lab[l_] : lab[R];
      lab[i] = lb;
    }
  }
  __syncthreads();

  // ---- 9. unsort: per original element, lower-bound lookup ----
  for (int s = 0; s < VPT; ++s) {
    int n = tid + s * TB;
    float v = x[n];
    float fb = (v - mn) * inv;
    int b = (int)fb;
    if (fb < 0.f) b = 0;
    if (b > NB - 1) b = NB - 1;
    int p = b ? (int)offs[b - 1] : 0;
    while (xs[p] < v) ++p;            // labels of equal values are equal
    labels[((size_t)(bd >> 6) * NPTS + n) * NDIM + (bd & 63)] = lab[p];
  }
}

// ---------------- per-batch exclusive prefix of cluster counts ----------------
__global__ void koffs(const int* __restrict__ ncl, int* __restrict__ off) {
  int lane = threadIdx.x & 63;
  int w = threadIdx.x >> 6;            // batch
  int v = ncl[w * 64 + lane];
  int incl = v;
  for (int d = 1; d < 64; d <<= 1) {
    int u = __shfl_up(incl, d);
    if (lane >= d) incl += u;
  }
  off[w * 64 + lane] = incl - v;       // exclusive
}

// ---------------- scatter 1.0 into incidence matrix ----------------
__global__ void kscatter(const short* __restrict__ labels, const int* __restrict__ off,
                         float* __restrict__ out) {
  int tid = threadIdx.x;
  int row = blockIdx.x * 4 + (tid >> 6);   // (b*NPTS + n)
  int d   = tid & 63;
  int b   = row >> 14;                     // NPTS = 2^14
  int lb  = labels[(size_t)row * NDIM + d];
  if (lb >= 0) {
    int col = lb + off[b * NDIM + d];
    if (col < NCMAX) out[(size_t)row * NCMAX + col] = 1.0f;
  }
}

extern "C" void kernel_launch(void* const* d_in, const int* in_sizes, int n_in,
                              void* d_out, int out_size, void* d_ws, size_t ws_size,
                              hipStream_t stream) {
  const float* feat = (const float*)d_in[0];
  float* out = (float*)d_out;

  char* ws = (char*)d_ws;
  float* xt     = (float*)ws;                                            // 4 MB
  short* labels = (short*)(ws + (size_t)NBATCH * NPTS * NDIM * 4);       // 16 MB
  int*   ncl    = (int*)(ws + (size_t)NBATCH * NPTS * NDIM * 4
                            + (size_t)NBATCH * NPTS * NDIM * 2);         // 2 KB
  int*   off    = ncl + NBATCH * NDIM;

  hipMemsetAsync(d_out, 0, (size_t)out_size * sizeof(float), stream);
  ktrans  <<<NBATCH * (NPTS / 64), 256, 0, stream>>>(feat, xt);
  kdbscan <<<NBATCH * NDIM, TB, 0, stream>>>(xt, labels, ncl);
  koffs   <<<1, 512, 0, stream>>>(ncl, off);
  kscatter<<<(NBATCH * NPTS) / 4, 256, 0, stream>>>(labels, off, out);
}

// Round 2
// 166.051 us; speedup vs baseline: 2.2290x; 2.2290x over previous
//
#include <hip/hip_runtime.h>

#define NPTS   16384
#define NDIM   64
#define NBATCH 8
#define TB     1024
#define VPT    16      // NPTS / TB
#define NB     8192    // histogram bins
#define BPT    8       // NB / TB
#define EPSF   0.1f
#define MINS   5
#define NCMAX  512
#define BIGI   0x3fffffff

// LDS swizzles: spread per-thread-contiguous accesses across banks (bijective XOR)
__device__ __forceinline__ int phys(int i)  { return i ^ ((i >> 5) & 15); }          // float array
__device__ __forceinline__ int lphys(int i) { return i ^ (((i >> 6) & 31) << 1); }   // short array

__device__ __forceinline__ int binof(float x, float mn, float inv) {
  float fb = (x - mn) * inv;
  int b = (int)fb;
  if (fb < 0.f) b = 0;
  if (b > NB - 1) b = NB - 1;
  return b;
}

// ---------------- transpose (B,N,D) -> (B,D,N) ----------------
__global__ void ktrans(const float* __restrict__ f, float* __restrict__ xt) {
  __shared__ float tile[64][65];
  int blk = blockIdx.x;
  int b   = blk >> 8;
  int n0  = (blk & 255) << 6;
  for (int i = threadIdx.x; i < 64 * 64; i += 256) {
    int n = i >> 6, d = i & 63;
    tile[n][d] = f[((size_t)b * NPTS + n0 + n) * NDIM + d];
  }
  __syncthreads();
  for (int i = threadIdx.x; i < 64 * 64; i += 256) {
    int d = i >> 6, n = i & 63;
    xt[((size_t)b * NDIM + d) * NPTS + n0 + n] = tile[n][d];
  }
}

// forward-scan monoid
struct FS { int h; float f; float l; int li; int c; };
__device__ __forceinline__ FS fsid() { FS r; r.h = 0; r.f = 0.f; r.l = 0.f; r.li = -1; r.c = 0; return r; }
__device__ __forceinline__ FS fscomb(FS a, FS b) {
  FS r;
  r.h  = a.h | b.h;
  r.f  = a.h ? a.f : b.f;
  r.l  = b.h ? b.l : a.l;
  r.li = b.h ? b.li : a.li;
  int gap = (a.h && b.h && ((b.f - a.l) > EPSF)) ? 1 : 0;
  r.c  = a.c + b.c + gap;
  return r;
}

// ---------------- per-(b,d) exact 1-D DBSCAN ----------------
__global__ void __launch_bounds__(TB) kdbscan(const float* __restrict__ xt,
                                              short* __restrict__ labels,
                                              int* __restrict__ nclg) {
  const int tid  = threadIdx.x;
  const int lane = tid & 63;
  const int wid  = tid >> 6;
  const int bd   = blockIdx.x;
  const float* __restrict__ x = xt + (size_t)bd * NPTS;

  __shared__ float xs[NPTS];            // 64 KB (phys-swizzled)
  __shared__ unsigned int hist[NB];     // 32 KB, later aliased as lab[]
  __shared__ unsigned int offs[NB];     // 32 KB
  __shared__ float wmn[16], wmx[16];
  __shared__ unsigned int wsum[16];
  __shared__ int   sh[16];  __shared__ float sf[16], sl[16];
  __shared__ int   sli[16]; __shared__ int   sc[16];
  __shared__ int   wri[16]; __shared__ float wrv[16];
  short* lab = (short*)hist;            // lphys-swizzled labels per sorted position

  // ---- 1. load into registers + min/max ----
  float v[VPT];
  float mn = INFINITY, mx = -INFINITY;
  #pragma unroll
  for (int s = 0; s < VPT; ++s) {
    v[s] = x[tid + s * TB];
    mn = fminf(mn, v[s]); mx = fmaxf(mx, v[s]);
  }
  for (int d = 1; d < 64; d <<= 1) {
    mn = fminf(mn, __shfl_xor(mn, d));
    mx = fmaxf(mx, __shfl_xor(mx, d));
  }
  if (lane == 0) { wmn[wid] = mn; wmx[wid] = mx; }
  __syncthreads();
  mn = wmn[0]; mx = wmx[0];
  for (int w = 1; w < 16; ++w) { mn = fminf(mn, wmn[w]); mx = fmaxf(mx, wmx[w]); }
  float range = mx - mn;
  float inv = (range > 0.f) ? ((float)NB / range) : 0.f;

  // ---- 2. histogram ----
  for (int i = tid; i < NB; i += TB) hist[i] = 0u;
  __syncthreads();
  #pragma unroll
  for (int s = 0; s < VPT; ++s) atomicAdd(&hist[binof(v[s], mn, inv)], 1u);
  __syncthreads();

  // ---- 3. exclusive prefix sum -> offs = bin starts (hist kept intact) ----
  unsigned int loc[BPT];
  unsigned int run = 0;
  const int bbase = tid * BPT;
  #pragma unroll
  for (int j = 0; j < BPT; ++j) { loc[j] = run; run += hist[bbase + j]; }
  unsigned int incl = run;
  for (int d = 1; d < 64; d <<= 1) {
    unsigned int u = __shfl_up(incl, d);
    if (lane >= d) incl += u;
  }
  unsigned int exc = __shfl_up(incl, 1);
  if (lane == 0) exc = 0u;
  if (lane == 63) wsum[wid] = incl;
  __syncthreads();
  unsigned int wb = 0;
  for (int w = 0; w < wid; ++w) wb += wsum[w];
  unsigned int tb0 = wb + exc;
  #pragma unroll
  for (int j = 0; j < BPT; ++j) offs[bbase + j] = tb0 + loc[j];
  __syncthreads();

  // ---- 4. scatter into bins (offs -> bin ends) ----
  int pos[VPT];
  #pragma unroll
  for (int s = 0; s < VPT; ++s) {
    int b = binof(v[s], mn, inv);
    int p = (int)atomicAdd(&offs[b], 1u);
    pos[s] = p;
    xs[phys(p)] = v[s];
  }
  __syncthreads();

  // ---- 5. parallel rank within bin -> exact sorted position of OWN elements ----
  int tgt[VPT];
  #pragma unroll
  for (int s = 0; s < VPT; ++s) {
    int b  = binof(v[s], mn, inv);
    int e0 = (int)offs[b];
    int s0 = e0 - (int)hist[b];
    float vv = v[s]; int pp = pos[s];
    int r = 0;
    for (int j = s0; j < e0; ++j) {
      float xj = xs[phys(j)];
      r += (xj < vv || (xj == vv && j < pp)) ? 1 : 0;
    }
    tgt[s] = s0 + r;
  }
  __syncthreads();
  // ---- 6. write sorted order (permutation, race-free after barrier) ----
  #pragma unroll
  for (int s = 0; s < VPT; ++s) xs[phys(tgt[s])] = v[s];
  __syncthreads();

  // ---- 7. core flags via 5-point sliding window (exact: count>=5 <=> some
  //         5-run containing i lies inside [xi-eps, xi+eps]) ----
  const int p0 = tid * VPT;
  float w[VPT + 8];
  #pragma unroll
  for (int k = 0; k < VPT + 8; ++k) {
    int i = p0 - 4 + k;
    w[k] = (i < 0) ? -INFINITY : ((i >= NPTS) ? INFINITY : xs[phys(i)]);
  }
  unsigned int coremask = 0u;
  #pragma unroll
  for (int s = 0; s < VPT; ++s) {
    float xi = w[s + 4];
    float lo = xi - EPSF, hi = xi + EPSF;
    bool core = false;
    #pragma unroll
    for (int t = 0; t < MINS; ++t)
      core |= (w[s + 4 - t] >= lo) && (w[s + 8 - t] <= hi);
    if (core) coremask |= (1u << s);
  }

  // ---- 8. forward scan: prev core val/idx + cluster ids ----
  FS ch = fsid();
  #pragma unroll
  for (int s = 0; s < VPT; ++s) {
    if ((coremask >> s) & 1u) {
      float xv = w[s + 4];
      if (!ch.h) { ch.h = 1; ch.f = xv; }
      else if ((xv - ch.l) > EPSF) ++ch.c;
      ch.l = xv; ch.li = p0 + s;
    }
  }
  FS cur = ch;
  for (int d = 1; d < 64; d <<= 1) {
    FS u;
    u.h  = __shfl_up(cur.h, d);
    u.f  = __shfl_up(cur.f, d);
    u.l  = __shfl_up(cur.l, d);
    u.li = __shfl_up(cur.li, d);
    u.c  = __shfl_up(cur.c, d);
    FS cmb = fscomb(u, cur);
    if (lane >= d) cur = cmb;
  }
  FS exs;
  exs.h  = __shfl_up(cur.h, 1);
  exs.f  = __shfl_up(cur.f, 1);
  exs.l  = __shfl_up(cur.l, 1);
  exs.li = __shfl_up(cur.li, 1);
  exs.c  = __shfl_up(cur.c, 1);
  if (lane == 0) exs = fsid();
  if (lane == 63) { sh[wid] = cur.h; sf[wid] = cur.f; sl[wid] = cur.l; sli[wid] = cur.li; sc[wid] = cur.c; }
  __syncthreads();
  FS pre = fsid();
  for (int w2 = 0; w2 < wid; ++w2) {
    FS t; t.h = sh[w2]; t.f = sf[w2]; t.l = sl[w2]; t.li = sli[w2]; t.c = sc[w2];
    pre = fscomb(pre, t);
  }
  FS sp = fscomb(pre, exs);

  float P  = sp.h ? sp.l  : -INFINITY;
  int   Pi = sp.h ? sp.li : -1;
  int starts = sp.h ? (sp.c + 1) : 0;
  int   li[VPT];
  float lv[VPT];
  #pragma unroll
  for (int s = 0; s < VPT; ++s) {
    int i = p0 + s;
    if ((coremask >> s) & 1u) {
      float xv = w[s + 4];
      if ((xv - P) > EPSF) ++starts;
      P = xv; Pi = i;
      lab[lphys(i)] = (short)(starts - 1);
    }
    li[s] = Pi; lv[s] = P;
  }
  if (tid == TB - 1) nclg[bd] = starts;

  // ---- 9. backward scan: next core (idx,val); border labels ----
  int fi_ = BIGI; float fv_ = 0.f;
  #pragma unroll
  for (int s = VPT - 1; s >= 0; --s)
    if ((coremask >> s) & 1u) { fi_ = p0 + s; fv_ = w[s + 4]; }
  int ri = fi_; float rv = fv_;
  for (int d = 1; d < 64; d <<= 1) {
    int ui = __shfl_down(ri, d); float uv = __shfl_down(rv, d);
    if (lane < 64 - d && ui < ri) { ri = ui; rv = uv; }
  }
  int rei = __shfl_down(ri, 1); float rev = __shfl_down(rv, 1);
  if (lane == 63) rei = BIGI;
  if (lane == 0) { wri[wid] = ri; wrv[wid] = rv; }
  __syncthreads();   // also makes core labels visible
  int Ri = rei; float Rv = rev;
  for (int w2 = wid + 1; w2 < 16; ++w2)
    if (wri[w2] < Ri) { Ri = wri[w2]; Rv = wrv[w2]; }
  #pragma unroll
  for (int s = VPT - 1; s >= 0; --s) {
    int i = p0 + s;
    if ((coremask >> s) & 1u) { Ri = i; Rv = w[s + 4]; }
    else {
      float xi = w[s + 4];
      float dl = xi - lv[s];                       // +inf if no left core
      float dr = (Ri < NPTS) ? (Rv - xi) : INFINITY;
      short lbv = -1;
      if (fminf(dl, dr) <= EPSF)
        lbv = (dl <= dr) ? lab[lphys(li[s])] : lab[lphys(Ri)];
      lab[lphys(i)] = lbv;
    }
  }
  __syncthreads();

  // ---- 10. unsort via tgt (exact, no search); coalesced (b,d,n) writes ----
  #pragma unroll
  for (int s = 0; s < VPT; ++s)
    labels[(size_t)bd * NPTS + tid + s * TB] = lab[lphys(tgt[s])];
}

// ------- per-batch cluster-count prefix + inverse col->(dim,label) map -------
__global__ void koffs(const int* __restrict__ ncl, int* __restrict__ colmap) {
  int lane = threadIdx.x & 63;
  int b    = threadIdx.x >> 6;         // 8 batches, 512 threads
  int vcnt = ncl[b * 64 + lane];
  int incl = vcnt;
  for (int d = 1; d < 64; d <<= 1) {
    int u = __shfl_up(incl, d);
    if (lane >= d) incl += u;
  }
  int off = incl - vcnt;               // exclusive prefix
  int* cm = colmap + b * NCMAX;
  for (int k = lane; k < NCMAX; k += 64) cm[k] = -1;
  __syncthreads();
  for (int k = 0; k < vcnt; ++k) {
    int col = off + k;
    if (col < NCMAX) cm[col] = lane | (k << 8);
  }
}

// ---------------- fused zero+scatter: write full output rows ----------------
__global__ void __launch_bounds__(TB) kout(const short* __restrict__ labels,
                                           const int* __restrict__ colmap,
                                           float* __restrict__ out) {
  const int tid  = threadIdx.x;
  const int lane = tid & 63;
  const int wid  = tid >> 6;
  const int b    = blockIdx.x >> 5;
  const int n0   = (blockIdx.x & 31) * 512 + wid * 32;

  int cm[8];
  const int* cmb = colmap + b * NCMAX;
  #pragma unroll
  for (int k = 0; k < 8; ++k) {
    int col = (k < 4) ? (lane * 4 + k) : (256 + lane * 4 + (k - 4));
    cm[k] = cmb[col];
  }
  const short* lb_b = labels + (size_t)b * NDIM * NPTS;

  for (int r = 0; r < 32; ++r) {
    int n = n0 + r;
    float o[8];
    #pragma unroll
    for (int k = 0; k < 8; ++k) {
      int m = cm[k];
      float val = 0.f;
      if (m >= 0) {
        int d  = m & 255;
        int kk = m >> 8;
        val = (lb_b[(size_t)d * NPTS + n] == (short)kk) ? 1.0f : 0.0f;
      }
      o[k] = val;
    }
    float4* op = (float4*)(out + ((size_t)b * NPTS + n) * NCMAX);
    op[lane]      = make_float4(o[0], o[1], o[2], o[3]);
    op[64 + lane] = make_float4(o[4], o[5], o[6], o[7]);
  }
}

extern "C" void kernel_launch(void* const* d_in, const int* in_sizes, int n_in,
                              void* d_out, int out_size, void* d_ws, size_t ws_size,
                              hipStream_t stream) {
  const float* feat = (const float*)d_in[0];
  float* out = (float*)d_out;

  char* ws = (char*)d_ws;
  float* xt     = (float*)ws;                                            // 4 MB
  short* labels = (short*)(ws + (size_t)NBATCH * NPTS * NDIM * 4);       // 16 MB (b,d,n)
  int*   ncl    = (int*)(ws + (size_t)NBATCH * NPTS * NDIM * 4
                            + (size_t)NBATCH * NPTS * NDIM * 2);         // 2 KB
  int*   colmap = ncl + NBATCH * NDIM;                                   // 16 KB

  ktrans  <<<NBATCH * (NPTS / 64), 256, 0, stream>>>(feat, xt);
  kdbscan <<<NBATCH * NDIM, TB, 0, stream>>>(xt, labels, ncl);
  koffs   <<<1, 512, 0, stream>>>(ncl, colmap);
  kout    <<<NBATCH * 32, TB, 0, stream>>>(labels, colmap, out);
}